// Round 1
// baseline (185.726 us; speedup 1.0000x reference)
//
#include <hip/hip_runtime.h>

// Scatter rows of `in` (B x TRIU_LEN) into upper triangle of out (B x N x N).
// triu_indices order is row-major: row i starts at offset i*N - i*(i-1)/2.
// Pure memory-bound: 512 MiB write + 256 MiB read -> ~128 us floor @ 6.3 TB/s.

#define MATSIZE 2048
#define TRIU_LEN 2098176  // 2048*2049/2

__global__ __launch_bounds__(256) void triu_scatter_kernel(
    const float* __restrict__ in, float* __restrict__ out, int total4) {
    int idx = blockIdx.x * blockDim.x + threadIdx.x;
    int stride = gridDim.x * blockDim.x;
    for (int q = idx; q < total4; q += stride) {
        // 2048*2048/4 = 2^20 float4 per matrix; 2048/4 = 512 = 2^9 float4 per row.
        int b   = q >> 20;
        int rem = q & ((1 << 20) - 1);
        int i   = rem >> 9;           // row
        int j   = (rem & 511) << 2;   // first col of this quad
        // input row start for row i of batch b
        int row_off = i * MATSIZE - (i * (i - 1)) / 2;   // < 2^22, fits int
        const float* src = in + (size_t)b * TRIU_LEN + row_off;
        float4 v;
        if (j >= i) {
            // whole quad in the triangle; src index = (j - i) .. (j - i + 3)
            const float* p = src + (j - i);
            v.x = p[0]; v.y = p[1]; v.z = p[2]; v.w = p[3];
        } else if (j + 3 < i) {
            v = make_float4(0.f, 0.f, 0.f, 0.f);
        } else {
            // diagonal straddle (at most one quad per row)
            v.x = (j + 0 >= i) ? src[j + 0 - i] : 0.f;
            v.y = (j + 1 >= i) ? src[j + 1 - i] : 0.f;
            v.z = (j + 2 >= i) ? src[j + 2 - i] : 0.f;
            v.w = (j + 3 >= i) ? src[j + 3 - i] : 0.f;
        }
        reinterpret_cast<float4*>(out)[q] = v;
    }
}

extern "C" void kernel_launch(void* const* d_in, const int* in_sizes, int n_in,
                              void* d_out, int out_size, void* d_ws, size_t ws_size,
                              hipStream_t stream) {
    const float* in = (const float*)d_in[0];
    float* out = (float*)d_out;
    const int total4 = out_size / 4;          // 33,554,432 float4 stores
    const int block = 256;
    const int grid = 2048;                    // 256 CU x 8 blocks, grid-stride
    triu_scatter_kernel<<<grid, block, 0, stream>>>(in, out, total4);
}

// Round 3
// 181.700 us; speedup vs baseline: 1.0222x; 1.0222x over previous
//
#include <hip/hip_runtime.h>

// Scatter rows of `in` (B x TRIU_LEN) into upper triangle of out (B x N x N).
// triu row-major: row i starts at input offset i*N - i*(i-1)/2.
// Memory-bound: 256 MiB read + 512 MiB write -> ~122 us floor @ 6.3 TB/s.
//
// Key facts exploited:
//  - 512 quads/row = exactly 8 waves/row -> row index i is wave-uniform,
//    branch divergence only in the single diagonal-straddle wave per row.
//  - gfx9+/CDNA multi-dword global loads need only 4B alignment, so the
//    (j-i)-shifted read can be ONE global_load_dwordx4 instead of 4 dwords.
//  - zero reuse -> nontemporal hints on both streams.
//  - __builtin_nontemporal_* needs a clang ext_vector type, not HIP float4.

#define MATSIZE 2048
#define TRIU_LEN 2098176  // 2048*2049/2

typedef float vf4 __attribute__((ext_vector_type(4)));

__global__ __launch_bounds__(256) void triu_scatter_kernel(
    const float* __restrict__ in, float* __restrict__ out, int total4) {
    int idx = blockIdx.x * blockDim.x + threadIdx.x;
    int stride = gridDim.x * blockDim.x;
    for (int q = idx; q < total4; q += stride) {
        // 2^20 quads per matrix; 2^9 quads per row.
        int b   = q >> 20;
        int rem = q & ((1 << 20) - 1);
        int i   = rem >> 9;           // row (wave-uniform)
        int j   = (rem & 511) << 2;   // first col of this quad
        int row_off = i * MATSIZE - (i * (i - 1)) / 2;   // fits int
        const float* src = in + (size_t)b * TRIU_LEN + row_off;
        vf4 v;
        if (j >= i) {
            // whole quad in triangle: single dwordx4 (4B-aligned is HW-legal)
            v = __builtin_nontemporal_load(
                    reinterpret_cast<const vf4*>(src + (j - i)));
        } else if (j + 3 < i) {
            v = (vf4){0.f, 0.f, 0.f, 0.f};
        } else {
            // diagonal straddle (one quad per row)
            v.x = (j + 0 >= i) ? src[j + 0 - i] : 0.f;
            v.y = (j + 1 >= i) ? src[j + 1 - i] : 0.f;
            v.z = (j + 2 >= i) ? src[j + 2 - i] : 0.f;
            v.w = (j + 3 >= i) ? src[j + 3 - i] : 0.f;
        }
        __builtin_nontemporal_store(v, reinterpret_cast<vf4*>(out) + q);
    }
}

extern "C" void kernel_launch(void* const* d_in, const int* in_sizes, int n_in,
                              void* d_out, int out_size, void* d_ws, size_t ws_size,
                              hipStream_t stream) {
    const float* in = (const float*)d_in[0];
    float* out = (float*)d_out;
    const int total4 = out_size / 4;          // 33,554,432 float4 stores
    const int block = 256;
    const int grid = 2048;                    // 256 CU x 8 blocks, grid-stride
    triu_scatter_kernel<<<grid, block, 0, stream>>>(in, out, total4);
}